// Round 1
// baseline (11.132 us; speedup 1.0000x reference)
//
#include <hip/hip_runtime.h>

// AE loss: tags [B,N,1] f32, joints [B,P,J,2] i32 (flat_idx, vis)
// outputs: push [B], pull [B]  -> d_out = [push(32) | pull(32)] f32
#define AE_B 32
#define AE_N (17 * 256 * 256)
#define AE_P 30
#define AE_J 17

__global__ __launch_bounds__(64) void ae_loss_kernel(
    const float* __restrict__ tags,
    const int*   __restrict__ joints,
    float*       __restrict__ out)
{
    const int b = blockIdx.x;
    const int t = threadIdx.x;

    __shared__ float s_mean[AE_P];
    __shared__ float s_valid[AE_P];
    __shared__ float s_pull[AE_P];

    const float* tb = tags   + (size_t)b * AE_N;
    const int*   jb = joints + (size_t)b * AE_P * AE_J * 2;

    if (t < AE_P) {
        // one person per lane: gather 17 (idx, vis) pairs and tag values
        const int* jp = jb + t * AE_J * 2;
        float g[AE_J], v[AE_J];
        float cnt = 0.f, sum = 0.f;
        #pragma unroll
        for (int j = 0; j < AE_J; ++j) {
            // 8-byte aligned (idx, vis) pair
            int2 iv = *reinterpret_cast<const int2*>(jp + 2 * j);
            float vf = (iv.y > 0) ? 1.f : 0.f;
            float gv = tb[iv.x];     // gather; masked by vf below
            g[j] = gv;
            v[j] = vf;
            cnt += vf;
            sum += gv * vf;
        }
        const float safe = fmaxf(cnt, 1.f);
        const float mean = sum / safe;
        float pull = 0.f;
        #pragma unroll
        for (int j = 0; j < AE_J; ++j) {
            float d = g[j] - mean;
            pull += d * d * v[j];
        }
        pull /= safe;
        s_mean[t]  = mean;
        s_valid[t] = (cnt > 0.f) ? 1.f : 0.f;
        s_pull[t]  = pull;
    }
    __syncthreads();

    // all 64 lanes split the P*P = 900 push pairs
    float psum = 0.f;
    for (int pair = t; pair < AE_P * AE_P; pair += 64) {
        int p = pair / AE_P;
        int q = pair - p * AE_P;
        float d = s_mean[p] - s_mean[q];
        psum += expf(-d * d) * s_valid[p] * s_valid[q];
    }
    // wave-64 butterfly reduce
    #pragma unroll
    for (int off = 32; off > 0; off >>= 1)
        psum += __shfl_down(psum, off);

    if (t == 0) {
        float num = 0.f, pull_sum = 0.f;
        for (int p = 0; p < AE_P; ++p) {
            num      += s_valid[p];
            pull_sum += s_pull[p] * s_valid[p];
        }
        const float pull  = pull_sum / fmaxf(num, 1.f);
        const float denom = fmaxf((num - 1.f) * num, 1.f);
        const float push  = (num > 1.f) ? (psum - num) / denom * 0.5f : 0.f;
        out[b]        = push;   // output 0: push
        out[AE_B + b] = pull;   // output 1: pull
    }
}

extern "C" void kernel_launch(void* const* d_in, const int* in_sizes, int n_in,
                              void* d_out, int out_size, void* d_ws, size_t ws_size,
                              hipStream_t stream) {
    const float* tags   = (const float*)d_in[0];
    const int*   joints = (const int*)d_in[1];
    float*       out    = (float*)d_out;
    ae_loss_kernel<<<AE_B, 64, 0, stream>>>(tags, joints, out);
}

// Round 2
// 9.305 us; speedup vs baseline: 1.1964x; 1.1964x over previous
//
#include <hip/hip_runtime.h>

// AE loss: tags [B,N,1] f32, joints [B,P,J,2] i32 (flat_idx, vis)
// outputs: push [B], pull [B]  -> d_out = [push(32) | pull(32)] f32
#define AE_B 32
#define AE_N (17 * 256 * 256)
#define AE_P 30
#define AE_J 17
#define AE_JI (AE_P * AE_J * 2)   // 1020 ints per batch, = 255 * int4 exactly

__global__ __launch_bounds__(64) void ae_loss_kernel(
    const float* __restrict__ tags,
    const int*   __restrict__ joints,
    float*       __restrict__ out)
{
    const int b = blockIdx.x;
    const int t = threadIdx.x;

    __shared__ int   s_j[AE_JI];       // staged joints for this batch
    __shared__ float s_mean[AE_P];
    __shared__ float s_valid[AE_P];
    __shared__ float s_pull[AE_P];

    const float* tb = tags + (size_t)b * AE_N;

    // coalesced stage of this batch's joints: 255 int4 loads across the wave
    // (batch slice is 4080 B, 16B-aligned since 4080 % 16 == 0)
    {
        const int4* jb4 = reinterpret_cast<const int4*>(joints + (size_t)b * AE_JI);
        #pragma unroll
        for (int i = 0; i < 4; ++i) {
            int slot = i * 64 + t;
            if (slot < AE_JI / 4) {
                int4 v = jb4[slot];
                s_j[slot * 4 + 0] = v.x;
                s_j[slot * 4 + 1] = v.y;
                s_j[slot * 4 + 2] = v.z;
                s_j[slot * 4 + 3] = v.w;
            }
        }
    }
    __syncthreads();

    if (t < AE_P) {
        // one person per lane: 17 (idx, vis) pairs from LDS, gather tag values
        const int* jp = s_j + t * AE_J * 2;
        float g[AE_J], v[AE_J];
        float cnt = 0.f, sum = 0.f;
        #pragma unroll
        for (int j = 0; j < AE_J; ++j) {
            int idx = jp[2 * j + 0];
            int vis = jp[2 * j + 1];
            float vf = (vis > 0) ? 1.f : 0.f;
            float gv = tb[idx];          // independent gathers, one vmcnt wait
            g[j] = gv;
            v[j] = vf;
            cnt += vf;
            sum += gv * vf;
        }
        const float safe = fmaxf(cnt, 1.f);
        const float mean = sum / safe;
        float pull = 0.f;
        #pragma unroll
        for (int j = 0; j < AE_J; ++j) {
            float d = g[j] - mean;
            pull += d * d * v[j];
        }
        pull /= safe;
        s_mean[t]  = mean;
        s_valid[t] = (cnt > 0.f) ? 1.f : 0.f;
        s_pull[t]  = pull;
    }
    __syncthreads();

    // all 64 lanes split the P*P = 900 push pairs
    float psum = 0.f;
    for (int pair = t; pair < AE_P * AE_P; pair += 64) {
        int p = pair / AE_P;
        int q = pair - p * AE_P;
        float d = s_mean[p] - s_mean[q];
        psum += __expf(-d * d) * s_valid[p] * s_valid[q];
    }
    // wave-64 butterfly reduce
    #pragma unroll
    for (int off = 32; off > 0; off >>= 1)
        psum += __shfl_down(psum, off);

    if (t == 0) {
        float num = 0.f, pull_sum = 0.f;
        for (int p = 0; p < AE_P; ++p) {
            num      += s_valid[p];
            pull_sum += s_pull[p] * s_valid[p];
        }
        const float pull  = pull_sum / fmaxf(num, 1.f);
        const float denom = fmaxf((num - 1.f) * num, 1.f);
        const float push  = (num > 1.f) ? (psum - num) / denom * 0.5f : 0.f;
        out[b]        = push;   // output 0: push
        out[AE_B + b] = pull;   // output 1: pull
    }
}

extern "C" void kernel_launch(void* const* d_in, const int* in_sizes, int n_in,
                              void* d_out, int out_size, void* d_ws, size_t ws_size,
                              hipStream_t stream) {
    const float* tags   = (const float*)d_in[0];
    const int*   joints = (const int*)d_in[1];
    float*       out    = (float*)d_out;
    ae_loss_kernel<<<AE_B, 64, 0, stream>>>(tags, joints, out);
}